// Round 7
// baseline (5775.834 us; speedup 1.0000x reference)
//
#include <hip/hip_runtime.h>
#include <hip/hip_bf16.h>

#define T_SEQ 1024
#define NB 128
#define HID 256
#define NEGINF_TGT (-(1 << 30))
#define TAGSTR 32  // u32 stride between tags = 128B (own cache line each)

typedef __attribute__((ext_vector_type(8))) short short8;
typedef __attribute__((ext_vector_type(4))) float f32x4;

__device__ __forceinline__ unsigned short f2bf(float f) {
  unsigned int u = __builtin_bit_cast(unsigned int, f);
  unsigned int r = (u + 0x7fffu + ((u >> 16) & 1u)) >> 16;
  return (unsigned short)r;
}

__device__ __forceinline__ float sigm(float x) { return 1.0f / (1.0f + expf(-x)); }

// ---- LLC-coherent transport (R3/R6-proven): agent-scope relaxed atomics ----
__device__ __forceinline__ short8 ld_h16(const unsigned short* p) {
  unsigned long long lo = __hip_atomic_load((const unsigned long long*)p,
                                            __ATOMIC_RELAXED, __HIP_MEMORY_SCOPE_AGENT);
  unsigned long long hi = __hip_atomic_load((const unsigned long long*)(p + 4),
                                            __ATOMIC_RELAXED, __HIP_MEMORY_SCOPE_AGENT);
  union { unsigned long long q[2]; short8 v; } u;
  u.q[0] = lo; u.q[1] = hi;
  return u.v;
}
__device__ __forceinline__ void st_h(unsigned short* p, unsigned short v) {
  __hip_atomic_store(p, v, __ATOMIC_RELAXED, __HIP_MEMORY_SCOPE_AGENT);
}

// Block-level publish: every wave drains its own vmem, block barrier orders
// all stores before the single tag store by thread 0.
__device__ __forceinline__ void publish_block(int* tag, int val) {
  asm volatile("s_waitcnt vmcnt(0) lgkmcnt(0)" ::: "memory");
  __syncthreads();
  if (threadIdx.x == 0)
    __hip_atomic_store(tag, val, __ATOMIC_RELAXED, __HIP_MEMORY_SCOPE_AGENT);
}

// dual wait: lanes with (lane>>2)&1==0 poll TAG1[lane&3] vs tgtA, others
// TAG2[lane&3] vs tgtB. Each tag on its own 128B line (4B at idx*TAGSTR).
__device__ __forceinline__ void wait_pair(const int* tg, int tgtA, int tgtB) {
  const int half = (threadIdx.x >> 2) & 1;
  const int* p = tg + (half * 4 + (threadIdx.x & 3)) * TAGSTR;
  const int tgt = half ? tgtB : tgtA;
  for (;;) {
    int v = __hip_atomic_load(p, __ATOMIC_RELAXED, __HIP_MEMORY_SCOPE_AGENT);
    if (__all(v >= tgt)) break;
  }
  asm volatile("" ::: "memory");
}

// ---------------- conv encoder (fp32) ----------------

__global__ void conv1_kernel(const float* __restrict__ imu, const float* __restrict__ k1,
                             const float* __restrict__ g1, const float* __restrict__ b1,
                             const float* __restrict__ m1, const float* __restrict__ v1,
                             float* __restrict__ y1) {
  int idx = blockIdx.x * 256 + threadIdx.x;   // [B][T][64]
  int c = idx & 63;
  int t = (idx >> 6) & (T_SEQ - 1);
  int b = idx >> 16;
  float acc = 0.f;
#pragma unroll
  for (int dt = 0; dt < 3; ++dt) {
    int tt = t + dt - 1;
    if (tt >= 0 && tt < T_SEQ) {
      const float* ip = imu + ((size_t)b * T_SEQ + tt) * 6;
#pragma unroll
      for (int ci = 0; ci < 6; ++ci)
        acc += ip[ci] * k1[(dt * 6 + ci) * 64 + c];
    }
  }
  float sc = g1[c] * rsqrtf(v1[c] + 1e-3f);
  float y = (acc - m1[c]) * sc + b1[c];
  y1[idx] = y > 0.f ? y : 0.1f * y;
}

__global__ __launch_bounds__(128) void conv2_kernel(
    const float* __restrict__ y1, const float* __restrict__ k2,
    const float* __restrict__ g2, const float* __restrict__ b2,
    const float* __restrict__ m2, const float* __restrict__ v2,
    float* __restrict__ y2) {
  __shared__ float yt[18 * 64];
  const int b = blockIdx.x >> 6;
  const int t0 = (blockIdx.x & 63) << 4;
  for (int i = threadIdx.x; i < 18 * 64; i += 128) {
    int r = i >> 6, ci = i & 63;
    int tt = t0 - 1 + r;
    yt[i] = (tt >= 0 && tt < T_SEQ) ? y1[((size_t)b * T_SEQ + tt) * 64 + ci] : 0.f;
  }
  __syncthreads();
  const int c = threadIdx.x;
  float acc[16];
#pragma unroll
  for (int u = 0; u < 16; ++u) acc[u] = 0.f;
  for (int ci = 0; ci < 64; ++ci) {
    float w0 = k2[(0 * 64 + ci) * 128 + c];
    float w1 = k2[(1 * 64 + ci) * 128 + c];
    float w2 = k2[(2 * 64 + ci) * 128 + c];
    float rv[18];
#pragma unroll
    for (int r = 0; r < 18; ++r) rv[r] = yt[r * 64 + ci];
#pragma unroll
    for (int u = 0; u < 16; ++u)
      acc[u] += rv[u] * w0 + rv[u + 1] * w1 + rv[u + 2] * w2;
  }
  float sc = g2[c] * rsqrtf(v2[c] + 1e-3f);
  float sh = b2[c] - m2[c] * sc;
#pragma unroll
  for (int u = 0; u < 16; ++u) {
    float y = acc[u] * sc + sh;
    y2[((size_t)b * T_SEQ + (t0 + u)) * 128 + c] = y > 0.f ? y : 0.1f * y;
  }
}

__global__ __launch_bounds__(128) void conv3_kernel(
    const float* __restrict__ y2, const float* __restrict__ k3,
    const float* __restrict__ g3, const float* __restrict__ b3,
    const float* __restrict__ m3, const float* __restrict__ v3,
    unsigned short* __restrict__ x) {  // x: [T][B][256] bf16
  __shared__ float yt[18 * 128];
  const int b = blockIdx.x >> 6;
  const int t0 = (blockIdx.x & 63) << 4;
  for (int i = threadIdx.x; i < 18 * 128; i += 128) {
    int r = i >> 7, ci = i & 127;
    int tt = t0 - 1 + r;
    yt[i] = (tt >= 0 && tt < T_SEQ) ? y2[((size_t)b * T_SEQ + tt) * 128 + ci] : 0.f;
  }
  __syncthreads();
  const int c0 = threadIdx.x;  // channels c0 and c0+128
  float acc0[16], acc1[16];
#pragma unroll
  for (int u = 0; u < 16; ++u) { acc0[u] = 0.f; acc1[u] = 0.f; }
  for (int ci = 0; ci < 128; ++ci) {
    float w00 = k3[(0 * 128 + ci) * 256 + c0];
    float w01 = k3[(1 * 128 + ci) * 256 + c0];
    float w02 = k3[(2 * 128 + ci) * 256 + c0];
    float w10 = k3[(0 * 128 + ci) * 256 + c0 + 128];
    float w11 = k3[(1 * 128 + ci) * 256 + c0 + 128];
    float w12 = k3[(2 * 128 + ci) * 256 + c0 + 128];
    float rv[18];
#pragma unroll
    for (int r = 0; r < 18; ++r) rv[r] = yt[r * 128 + ci];
#pragma unroll
    for (int u = 0; u < 16; ++u) {
      acc0[u] += rv[u] * w00 + rv[u + 1] * w01 + rv[u + 2] * w02;
      acc1[u] += rv[u] * w10 + rv[u + 1] * w11 + rv[u + 2] * w12;
    }
  }
  float sca = g3[c0] * rsqrtf(v3[c0] + 1e-3f);
  float sha = b3[c0] - m3[c0] * sca;
  float scb = g3[c0 + 128] * rsqrtf(v3[c0 + 128] + 1e-3f);
  float shb = b3[c0 + 128] - m3[c0 + 128] * scb;
#pragma unroll
  for (int u = 0; u < 16; ++u) {
    float ya = acc0[u] * sca + sha;
    float yb = acc1[u] * scb + shb;
    ya = ya > 0.f ? ya : 0.1f * ya;
    yb = yb > 0.f ? yb : 0.1f * yb;
    size_t base = ((size_t)(t0 + u) * NB + b) * HID;
    x[base + c0] = f2bf(ya);
    x[base + c0 + 128] = f2bf(yb);
  }
}

// ---------------- persistent pipelined LSTM ----------------
// 64 blocks x 256 threads (4 waves, 1 wave/SIMD, zero LDS arrays).
// Team = 8 blocks (4 L1 + 4 L2) = 16 batch rows. Wave = one 16-col panel
// (all 4 gates): pid = bn*4 + wv, panels 0..15 as in R6. Exchange protocol
// identical to R6 (agent-scope ring + monotone tags), but 4 publishes/chain
// (block-level, after __syncthreads) and each tag on its own 128B line.
// Dep graph: L1(ph) <- L1(ph-1), L2(ph-3);  L2(ph) <- L1(ph), L2(ph-1).

__global__ __launch_bounds__(256, 1) void lstm_kernel(
    const unsigned short* __restrict__ x,   // [T][NB][256] bf16
    const float* __restrict__ W1, const float* __restrict__ U1, const float* __restrict__ bl1,
    const float* __restrict__ W2, const float* __restrict__ U2, const float* __restrict__ bl2,
    unsigned short* __restrict__ hbufs,     // [8 teams][2 layers][4 slots][16p][16r][16c], zeroed
    int* __restrict__ tags,                 // [8 teams][8 tags x TAGSTR], zeroed
    float* __restrict__ out) {              // [128][256]
  const int team = blockIdx.x >> 3;
  const int sub = blockIdx.x & 7;           // 0..3 = L1 blocks, 4..7 = L2
  const bool is_l2 = sub >= 4;
  const int bn = sub & 3;
  const int wv = threadIdx.x >> 6;
  const int lane = threadIdx.x & 63;
  const int pid = (bn << 2) + wv;           // global 16-col panel 0..15
  const int j0 = pid << 4;
  const int b0 = team << 4;

  const float* Wx = is_l2 ? W2 : W1;
  const float* Wh = is_l2 ? U2 : U1;
  const float* bl = is_l2 ? bl2 : bl1;

  const int lo4 = lane & 15;
  const int klo = (lane >> 4) << 3;

  // ---- weights -> registers: wB[s][kk][g], s=0: W-path, s=1: U-path ----
  short8 wB[2][8][4];
  {
    const float* Wsrc[2] = {Wx, Wh};
#pragma unroll
    for (int s = 0; s < 2; ++s)
#pragma unroll
      for (int kk = 0; kk < 8; ++kk)
#pragma unroll
        for (int g = 0; g < 4; ++g) {
          short8 v;
#pragma unroll
          for (int e = 0; e < 8; ++e)
            v[e] = (short)f2bf(Wsrc[s][(size_t)(kk * 32 + klo + e) * 1024 + (g << 8) + j0 + lo4]);
          wB[s][kk][g] = v;
        }
  }

  float bias[4];
#pragma unroll
  for (int g = 0; g < 4; ++g) bias[g] = bl[(g << 8) + j0 + lo4];

  unsigned short* h1b = hbufs + (size_t)team * 32768;  // [4 slots][4096]
  unsigned short* h2b = h1b + 16384;
  int* tg = tags + team * 8 * TAGSTR;                  // tags 0..3 = L1, 4..7 = L2

  const int cbase = ((klo >> 4) << 8) + (lo4 << 4) + (klo & 8);
  const int row = ((lane >> 4) << 2);
  const int stoff = pid * 256 + row * 16 + lo4;

  float cst[4] = {0.f, 0.f, 0.f, 0.f};
  float oacc[4] = {0.f, 0.f, 0.f, 0.f};
  f32x4 acc[4];

  if (!is_l2) {
    // ---------------- layer-1 block ----------------
#pragma unroll
    for (int g = 0; g < 4; ++g) acc[g] = (f32x4){bias[g], bias[g], bias[g], bias[g]};
    {
      const unsigned short* xs = x + (size_t)(b0 + lo4) * HID + klo;
#pragma unroll
      for (int kk = 0; kk < 8; ++kk) {
        short8 a = *(const short8*)(xs + kk * 32);
#pragma unroll
        for (int g = 0; g < 4; ++g)
          acc[g] = __builtin_amdgcn_mfma_f32_16x16x32_bf16(a, wB[0][kk][g], acc[g], 0, 0, 0);
      }
    }

    for (int ph = 0; ph < T_SEQ; ++ph) {
      // peers' h1[ph-1] ready; ring guard: L2 consumed h1[ph-4]
      wait_pair(tg, ph, ph - 3);
      {
        const unsigned short* src = h1b + ((ph + 3) & 3) * 4096 + cbase;
        short8 av[8];
#pragma unroll
        for (int kk = 0; kk < 8; ++kk) av[kk] = ld_h16(src + kk * 512);
#pragma unroll
        for (int kk = 0; kk < 8; ++kk)
#pragma unroll
          for (int g = 0; g < 4; ++g)
            acc[g] = __builtin_amdgcn_mfma_f32_16x16x32_bf16(av[kk], wB[1][kk][g], acc[g], 0, 0, 0);
      }
      unsigned short* dst = h1b + (ph & 3) * 4096 + stoff;
#pragma unroll
      for (int q = 0; q < 4; ++q) {
        float iv = acc[0][q], fv = acc[1][q], gv = acc[2][q], ov = acc[3][q];
        float cn = sigm(fv) * cst[q] + sigm(iv) * tanhf(gv);
        float hn = sigm(ov) * tanhf(cn);
        cst[q] = cn;
        st_h(dst + q * 16, f2bf(hn));
      }
      short8 xv[8];
      if (ph + 1 < T_SEQ) {  // issue next x loads under the drain
        const unsigned short* xs = x + ((size_t)(ph + 1) * NB + b0 + lo4) * HID + klo;
#pragma unroll
        for (int kk = 0; kk < 8; ++kk) xv[kk] = *(const short8*)(xs + kk * 32);
      }
      publish_block(&tg[bn * TAGSTR], ph + 1);
      if (ph + 1 < T_SEQ) {  // shadow: acc = bias + x[ph+1] @ W1
#pragma unroll
        for (int g = 0; g < 4; ++g) acc[g] = (f32x4){bias[g], bias[g], bias[g], bias[g]};
#pragma unroll
        for (int kk = 0; kk < 8; ++kk)
#pragma unroll
          for (int g = 0; g < 4; ++g)
            acc[g] = __builtin_amdgcn_mfma_f32_16x16x32_bf16(xv[kk], wB[0][kk][g], acc[g], 0, 0, 0);
      }
    }
  } else {
    // ---------------- layer-2 block ----------------
    for (int ph = 0; ph < T_SEQ; ++ph) {
      wait_pair(tg, ph + 1, NEGINF_TGT);    // h1[ph] ready (early via pipeline)
#pragma unroll
      for (int g = 0; g < 4; ++g) acc[g] = (f32x4){bias[g], bias[g], bias[g], bias[g]};
      {
        const unsigned short* s1 = h1b + (ph & 3) * 4096 + cbase;
        short8 av[8];
#pragma unroll
        for (int kk = 0; kk < 8; ++kk) av[kk] = ld_h16(s1 + kk * 512);
#pragma unroll
        for (int kk = 0; kk < 8; ++kk)
#pragma unroll
          for (int g = 0; g < 4; ++g)
            acc[g] = __builtin_amdgcn_mfma_f32_16x16x32_bf16(av[kk], wB[0][kk][g], acc[g], 0, 0, 0);
      }
      wait_pair(tg, NEGINF_TGT, ph);        // peers' h2[ph-1] ready (serial path)
      {
        const unsigned short* s2 = h2b + ((ph + 3) & 3) * 4096 + cbase;
        short8 av[8];
#pragma unroll
        for (int kk = 0; kk < 8; ++kk) av[kk] = ld_h16(s2 + kk * 512);
#pragma unroll
        for (int kk = 0; kk < 8; ++kk)
#pragma unroll
          for (int g = 0; g < 4; ++g)
            acc[g] = __builtin_amdgcn_mfma_f32_16x16x32_bf16(av[kk], wB[1][kk][g], acc[g], 0, 0, 0);
      }
      unsigned short* dst = h2b + (ph & 3) * 4096 + stoff;
#pragma unroll
      for (int q = 0; q < 4; ++q) {
        float iv = acc[0][q], fv = acc[1][q], gv = acc[2][q], ov = acc[3][q];
        float cn = sigm(fv) * cst[q] + sigm(iv) * tanhf(gv);
        float hn = sigm(ov) * tanhf(cn);
        cst[q] = cn;
        st_h(dst + q * 16, f2bf(hn));
        oacc[q] += hn;
      }
      publish_block(&tg[(4 + bn) * TAGSTR], ph + 1);
    }
#pragma unroll
    for (int q = 0; q < 4; ++q)
      out[(size_t)(b0 + row + q) * HID + j0 + lo4] = oacc[q] * (1.0f / T_SEQ);
  }
}

// ---------------- host ----------------

extern "C" void kernel_launch(void* const* d_in, const int* in_sizes, int n_in,
                              void* d_out, int out_size, void* d_ws, size_t ws_size,
                              hipStream_t stream) {
  const float* imu = (const float*)d_in[0];
  const float* k1 = (const float*)d_in[1];
  const float* g1 = (const float*)d_in[2];
  const float* b1 = (const float*)d_in[3];
  const float* m1 = (const float*)d_in[4];
  const float* v1 = (const float*)d_in[5];
  const float* k2 = (const float*)d_in[6];
  const float* g2 = (const float*)d_in[7];
  const float* b2 = (const float*)d_in[8];
  const float* m2 = (const float*)d_in[9];
  const float* v2 = (const float*)d_in[10];
  const float* k3 = (const float*)d_in[11];
  const float* g3 = (const float*)d_in[12];
  const float* b3 = (const float*)d_in[13];
  const float* m3 = (const float*)d_in[14];
  const float* v3 = (const float*)d_in[15];
  const float* W1 = (const float*)d_in[16];
  const float* U1 = (const float*)d_in[17];
  const float* bl1 = (const float*)d_in[18];
  const float* W2 = (const float*)d_in[19];
  const float* U2 = (const float*)d_in[20];
  const float* bl2 = (const float*)d_in[21];

  char* ws = (char*)d_ws;
  // [0,64Mi) y2 fp32; [64Mi,96Mi) y1 fp32; [64Mi,128Mi) x bf16 (y1 dead after conv2);
  // [128Mi..) h rings (512Ki) + tags (8Ki).
  float* y2 = (float*)ws;
  float* y1 = (float*)(ws + (64u << 20));
  unsigned short* xq = (unsigned short*)(ws + (64u << 20));
  unsigned short* hbufs = (unsigned short*)(ws + (128u << 20));
  int* tags = (int*)(ws + (128u << 20) + (512u << 10));

  hipMemsetAsync(ws + (128u << 20), 0, (512u << 10) + 8192, stream);

  conv1_kernel<<<32768, 256, 0, stream>>>(imu, k1, g1, b1, m1, v1, y1);
  conv2_kernel<<<8192, 128, 0, stream>>>(y1, k2, g2, b2, m2, v2, y2);
  conv3_kernel<<<8192, 128, 0, stream>>>(y2, k3, g3, b3, m3, v3, xq);
  lstm_kernel<<<64, 256, 0, stream>>>(xq, W1, U1, bl1, W2, U2, bl2, hbufs, tags,
                                      (float*)d_out);
}

// Round 9
// 5362.698 us; speedup vs baseline: 1.0770x; 1.0770x over previous
//
#include <hip/hip_runtime.h>
#include <hip/hip_bf16.h>

#define T_SEQ 1024
#define NB 128
#define HID 256

typedef __attribute__((ext_vector_type(8))) short short8;
typedef __attribute__((ext_vector_type(4))) float f32x4;
typedef __attribute__((ext_vector_type(4))) unsigned int u32x4;

__device__ __forceinline__ unsigned short f2bf(float f) {
  unsigned int u = __builtin_bit_cast(unsigned int, f);
  unsigned int r = (u + 0x7fffu + ((u >> 16) & 1u)) >> 16;
  return (unsigned short)r;
}

__device__ __forceinline__ float sigm(float x) { return 1.0f / (1.0f + expf(-x)); }

// ---------- self-validating h transport (fixed R8) ----------
// Ring slot layout: row-major [16 rows][256 cols] of u32 = (bf16<<16)|stamp.
// Lane's A-fragment = 8 contiguous words per kk at row*256 + kk*32 + klo.
// Single asm blob: 16 dwordx4 + vmcnt(0) INSIDE (no in-flight reg hazards).
__device__ __forceinline__ void poll_frag(const unsigned int* base, unsigned int stamp,
                                          short8 av[8]) {
  u32x4 t[16];
  for (;;) {
    asm volatile(
        "global_load_dwordx4 %0, %16, off sc0 sc1\n\t"
        "global_load_dwordx4 %1, %16, off offset:16 sc0 sc1\n\t"
        "global_load_dwordx4 %2, %16, off offset:128 sc0 sc1\n\t"
        "global_load_dwordx4 %3, %16, off offset:144 sc0 sc1\n\t"
        "global_load_dwordx4 %4, %16, off offset:256 sc0 sc1\n\t"
        "global_load_dwordx4 %5, %16, off offset:272 sc0 sc1\n\t"
        "global_load_dwordx4 %6, %16, off offset:384 sc0 sc1\n\t"
        "global_load_dwordx4 %7, %16, off offset:400 sc0 sc1\n\t"
        "global_load_dwordx4 %8, %16, off offset:512 sc0 sc1\n\t"
        "global_load_dwordx4 %9, %16, off offset:528 sc0 sc1\n\t"
        "global_load_dwordx4 %10, %16, off offset:640 sc0 sc1\n\t"
        "global_load_dwordx4 %11, %16, off offset:656 sc0 sc1\n\t"
        "global_load_dwordx4 %12, %16, off offset:768 sc0 sc1\n\t"
        "global_load_dwordx4 %13, %16, off offset:784 sc0 sc1\n\t"
        "global_load_dwordx4 %14, %16, off offset:896 sc0 sc1\n\t"
        "global_load_dwordx4 %15, %16, off offset:912 sc0 sc1\n\t"
        "s_waitcnt vmcnt(0)"
        : "=&v"(t[0]), "=&v"(t[1]), "=&v"(t[2]), "=&v"(t[3]),
          "=&v"(t[4]), "=&v"(t[5]), "=&v"(t[6]), "=&v"(t[7]),
          "=&v"(t[8]), "=&v"(t[9]), "=&v"(t[10]), "=&v"(t[11]),
          "=&v"(t[12]), "=&v"(t[13]), "=&v"(t[14]), "=&v"(t[15])
        : "v"(base)
        : "memory");
    unsigned int bad = 0;
#pragma unroll
    for (int i = 0; i < 16; ++i)
#pragma unroll
      for (int e = 0; e < 4; ++e) bad |= (t[i][e] ^ stamp) & 0xffffu;
    if (__all(bad == 0)) break;
    __builtin_amdgcn_s_sleep(1);
  }
#pragma unroll
  for (int kk = 0; kk < 8; ++kk) {
    short8 a;
#pragma unroll
    for (int e = 0; e < 4; ++e) {
      a[e] = (short)(t[2 * kk][e] >> 16);
      a[4 + e] = (short)(t[2 * kk + 1][e] >> 16);
    }
    av[kk] = a;
  }
}

__device__ __forceinline__ void st_hw(unsigned int* p, unsigned int v) {
  __hip_atomic_store(p, v, __ATOMIC_RELAXED, __HIP_MEMORY_SCOPE_AGENT);
}
__device__ __forceinline__ unsigned int ld_tag(const unsigned int* p) {
  return __hip_atomic_load(p, __ATOMIC_RELAXED, __HIP_MEMORY_SCOPE_AGENT);
}

// ---------------- conv encoder (fp32) ----------------

__global__ void conv1_kernel(const float* __restrict__ imu, const float* __restrict__ k1,
                             const float* __restrict__ g1, const float* __restrict__ b1,
                             const float* __restrict__ m1, const float* __restrict__ v1,
                             float* __restrict__ y1) {
  int idx = blockIdx.x * 256 + threadIdx.x;   // [B][T][64]
  int c = idx & 63;
  int t = (idx >> 6) & (T_SEQ - 1);
  int b = idx >> 16;
  float acc = 0.f;
#pragma unroll
  for (int dt = 0; dt < 3; ++dt) {
    int tt = t + dt - 1;
    if (tt >= 0 && tt < T_SEQ) {
      const float* ip = imu + ((size_t)b * T_SEQ + tt) * 6;
#pragma unroll
      for (int ci = 0; ci < 6; ++ci)
        acc += ip[ci] * k1[(dt * 6 + ci) * 64 + c];
    }
  }
  float sc = g1[c] * rsqrtf(v1[c] + 1e-3f);
  float y = (acc - m1[c]) * sc + b1[c];
  y1[idx] = y > 0.f ? y : 0.1f * y;
}

__global__ __launch_bounds__(128) void conv2_kernel(
    const float* __restrict__ y1, const float* __restrict__ k2,
    const float* __restrict__ g2, const float* __restrict__ b2,
    const float* __restrict__ m2, const float* __restrict__ v2,
    float* __restrict__ y2) {
  __shared__ float yt[18 * 64];
  const int b = blockIdx.x >> 6;
  const int t0 = (blockIdx.x & 63) << 4;
  for (int i = threadIdx.x; i < 18 * 64; i += 128) {
    int r = i >> 6, ci = i & 63;
    int tt = t0 - 1 + r;
    yt[i] = (tt >= 0 && tt < T_SEQ) ? y1[((size_t)b * T_SEQ + tt) * 64 + ci] : 0.f;
  }
  __syncthreads();
  const int c = threadIdx.x;
  float acc[16];
#pragma unroll
  for (int u = 0; u < 16; ++u) acc[u] = 0.f;
  for (int ci = 0; ci < 64; ++ci) {
    float w0 = k2[(0 * 64 + ci) * 128 + c];
    float w1 = k2[(1 * 64 + ci) * 128 + c];
    float w2 = k2[(2 * 64 + ci) * 128 + c];
    float rv[18];
#pragma unroll
    for (int r = 0; r < 18; ++r) rv[r] = yt[r * 64 + ci];
#pragma unroll
    for (int u = 0; u < 16; ++u)
      acc[u] += rv[u] * w0 + rv[u + 1] * w1 + rv[u + 2] * w2;
  }
  float sc = g2[c] * rsqrtf(v2[c] + 1e-3f);
  float sh = b2[c] - m2[c] * sc;
#pragma unroll
  for (int u = 0; u < 16; ++u) {
    float y = acc[u] * sc + sh;
    y2[((size_t)b * T_SEQ + (t0 + u)) * 128 + c] = y > 0.f ? y : 0.1f * y;
  }
}

__global__ __launch_bounds__(128) void conv3_kernel(
    const float* __restrict__ y2, const float* __restrict__ k3,
    const float* __restrict__ g3, const float* __restrict__ b3,
    const float* __restrict__ m3, const float* __restrict__ v3,
    unsigned short* __restrict__ x) {  // x: [T][B][256] bf16
  __shared__ float yt[18 * 128];
  const int b = blockIdx.x >> 6;
  const int t0 = (blockIdx.x & 63) << 4;
  for (int i = threadIdx.x; i < 18 * 128; i += 128) {
    int r = i >> 7, ci = i & 127;
    int tt = t0 - 1 + r;
    yt[i] = (tt >= 0 && tt < T_SEQ) ? y2[((size_t)b * T_SEQ + tt) * 128 + ci] : 0.f;
  }
  __syncthreads();
  const int c0 = threadIdx.x;  // channels c0 and c0+128
  float acc0[16], acc1[16];
#pragma unroll
  for (int u = 0; u < 16; ++u) { acc0[u] = 0.f; acc1[u] = 0.f; }
  for (int ci = 0; ci < 128; ++ci) {
    float w00 = k3[(0 * 128 + ci) * 256 + c0];
    float w01 = k3[(1 * 128 + ci) * 256 + c0];
    float w02 = k3[(2 * 128 + ci) * 256 + c0];
    float w10 = k3[(0 * 128 + ci) * 256 + c0 + 128];
    float w11 = k3[(1 * 128 + ci) * 256 + c0 + 128];
    float w12 = k3[(2 * 128 + ci) * 256 + c0 + 128];
    float rv[18];
#pragma unroll
    for (int r = 0; r < 18; ++r) rv[r] = yt[r * 128 + ci];
#pragma unroll
    for (int u = 0; u < 16; ++u) {
      acc0[u] += rv[u] * w00 + rv[u + 1] * w01 + rv[u + 2] * w02;
      acc1[u] += rv[u] * w10 + rv[u + 1] * w11 + rv[u + 2] * w12;
    }
  }
  float sca = g3[c0] * rsqrtf(v3[c0] + 1e-3f);
  float sha = b3[c0] - m3[c0] * sca;
  float scb = g3[c0 + 128] * rsqrtf(v3[c0 + 128] + 1e-3f);
  float shb = b3[c0 + 128] - m3[c0 + 128] * scb;
#pragma unroll
  for (int u = 0; u < 16; ++u) {
    float ya = acc0[u] * sca + sha;
    float yb = acc1[u] * scb + shb;
    ya = ya > 0.f ? ya : 0.1f * ya;
    yb = yb > 0.f ? yb : 0.1f * yb;
    size_t base = ((size_t)(t0 + u) * NB + b) * HID;
    x[base + c0] = f2bf(ya);
    x[base + c0 + 128] = f2bf(yb);
  }
}

// ---------------- persistent pipelined LSTM ----------------
// 256 blocks x 64 threads (R6 geometry, proven live). Team = 32 blocks
// (16 L1 + 16 L2), 16 batch rows. h ring: u32 (bf16<<16|stamp), row-major
// [team][layer][slot=ph&3][16 rows][256 cols]. Wait==load via stamped polls;
// producers never drain. Ring guard: ctag[pid] = consumed marks (L2 ->
// L1, slack 3, off critical path). Dep graph acyclic as R6.

__global__ __launch_bounds__(64, 1) void lstm_kernel(
    const unsigned short* __restrict__ x,   // [T][NB][256] bf16
    const float* __restrict__ W1, const float* __restrict__ U1, const float* __restrict__ bl1,
    const float* __restrict__ W2, const float* __restrict__ U2, const float* __restrict__ bl2,
    unsigned int* __restrict__ hrings,      // [8 teams][2][4][4096] u32, zeroed
    unsigned int* __restrict__ tags,        // [8 teams][32] u32, zeroed
    float* __restrict__ out) {              // [128][256]
  const int team = blockIdx.x >> 5;
  const int bid = blockIdx.x & 31;
  const bool is_l2 = bid >= 16;
  const int pid = bid & 15;
  const int j0 = pid << 4;
  const int lane = threadIdx.x;
  const int b0 = team << 4;

  const float* Wx = is_l2 ? W2 : W1;
  const float* Wh = is_l2 ? U2 : U1;
  const float* bl = is_l2 ? bl2 : bl1;

  const int lo4 = lane & 15;
  const int klo = (lane >> 4) << 3;

  // ---- weights -> registers: wB[s][kk][g], s=0: W-path, s=1: U-path ----
  short8 wB[2][8][4];
  {
    const float* Wsrc[2] = {Wx, Wh};
#pragma unroll
    for (int s = 0; s < 2; ++s)
#pragma unroll
      for (int kk = 0; kk < 8; ++kk)
#pragma unroll
        for (int g = 0; g < 4; ++g) {
          short8 v;
#pragma unroll
          for (int e = 0; e < 8; ++e)
            v[e] = (short)f2bf(Wsrc[s][(size_t)(kk * 32 + klo + e) * 1024 + (g << 8) + j0 + lo4]);
          wB[s][kk][g] = v;
        }
  }

  float bias[4];
#pragma unroll
  for (int g = 0; g < 4; ++g) bias[g] = bl[(g << 8) + j0 + lo4];

  unsigned int* h1b = hrings + (size_t)team * 32768;  // [4][4096] u32
  unsigned int* h2b = h1b + 16384;
  unsigned int* ctag = tags + team * 32;              // [16] consumed marks

  const int fbase = lo4 * 256 + klo;   // lane's fragment base word within a slot
  const int row = ((lane >> 4) << 2);  // D rows row..row+3
  // store words: (row+q)*256 + j0 + lo4

  float cst[4] = {0.f, 0.f, 0.f, 0.f};
  float oacc[4] = {0.f, 0.f, 0.f, 0.f};
  f32x4 acc[4];
  short8 av[8];

  if (!is_l2) {
    // ---------------- layer-1 block ----------------
    // prologue: acc = bias + x[0] @ W1
#pragma unroll
    for (int g = 0; g < 4; ++g) acc[g] = (f32x4){bias[g], bias[g], bias[g], bias[g]};
    {
      const unsigned short* xs = x + (size_t)(b0 + lo4) * HID + klo;
#pragma unroll
      for (int kk = 0; kk < 8; ++kk) {
        short8 a = *(const short8*)(xs + kk * 32);
#pragma unroll
        for (int g = 0; g < 4; ++g)
          acc[g] = __builtin_amdgcn_mfma_f32_16x16x32_bf16(a, wB[0][kk][g], acc[g], 0, 0, 0);
      }
    }

    for (int ph = 0; ph < T_SEQ; ++ph) {
      int gv = (int)ld_tag(&ctag[lane & 15]);   // guard value, in flight early
      if (ph > 0) {
        poll_frag(h1b + ((ph + 3) & 3) * 4096 + fbase, (unsigned)ph, av);  // h1[ph-1]
#pragma unroll
        for (int kk = 0; kk < 8; ++kk)
#pragma unroll
          for (int g = 0; g < 4; ++g)
            acc[g] = __builtin_amdgcn_mfma_f32_16x16x32_bf16(av[kk], wB[1][kk][g], acc[g], 0, 0, 0);
      }
      unsigned int stamp = (unsigned)(ph + 1);
      unsigned int pv[4];
#pragma unroll
      for (int q = 0; q < 4; ++q) {
        float iv = acc[0][q], fv = acc[1][q], gg = acc[2][q], ov = acc[3][q];
        float cn = sigm(fv) * cst[q] + sigm(iv) * tanhf(gg);
        float hn = sigm(ov) * tanhf(cn);
        cst[q] = cn;
        pv[q] = ((unsigned)f2bf(hn) << 16) | stamp;
      }
      // ring guard: L2 consumed h1[ph-4] (ctag >= ph-3); slack-3, rarely waits
      while (!__all(gv >= ph - 3)) {
        __builtin_amdgcn_s_sleep(1);
        gv = (int)ld_tag(&ctag[lane & 15]);
      }
      unsigned int* dst = h1b + (ph & 3) * 4096;
#pragma unroll
      for (int q = 0; q < 4; ++q) st_hw(dst + (row + q) * 256 + j0 + lo4, pv[q]);
      if (ph + 1 < T_SEQ) {  // shadow: acc = bias + x[ph+1] @ W1 (fire-and-forget stores above)
        const unsigned short* xs = x + ((size_t)(ph + 1) * NB + b0 + lo4) * HID + klo;
        short8 xv[8];
#pragma unroll
        for (int kk = 0; kk < 8; ++kk) xv[kk] = *(const short8*)(xs + kk * 32);
#pragma unroll
        for (int g = 0; g < 4; ++g) acc[g] = (f32x4){bias[g], bias[g], bias[g], bias[g]};
#pragma unroll
        for (int kk = 0; kk < 8; ++kk)
#pragma unroll
          for (int g = 0; g < 4; ++g)
            acc[g] = __builtin_amdgcn_mfma_f32_16x16x32_bf16(xv[kk], wB[0][kk][g], acc[g], 0, 0, 0);
      }
    }
  } else {
    // ---------------- layer-2 block ----------------
    // prologue (shadow for ph=0): consume h1[0], acc = bias + W2·h1[0]
    poll_frag(h1b + 0 * 4096 + fbase, 1u, av);
    if (lane == 0) st_hw(&ctag[pid], 1u);
#pragma unroll
    for (int g = 0; g < 4; ++g) acc[g] = (f32x4){bias[g], bias[g], bias[g], bias[g]};
#pragma unroll
    for (int kk = 0; kk < 8; ++kk)
#pragma unroll
      for (int g = 0; g < 4; ++g)
        acc[g] = __builtin_amdgcn_mfma_f32_16x16x32_bf16(av[kk], wB[0][kk][g], acc[g], 0, 0, 0);

    for (int ph = 0; ph < T_SEQ; ++ph) {
      if (ph > 0) {
        poll_frag(h2b + ((ph + 3) & 3) * 4096 + fbase, (unsigned)ph, av);  // h2[ph-1]
#pragma unroll
        for (int kk = 0; kk < 8; ++kk)
#pragma unroll
          for (int g = 0; g < 4; ++g)
            acc[g] = __builtin_amdgcn_mfma_f32_16x16x32_bf16(av[kk], wB[1][kk][g], acc[g], 0, 0, 0);
      }
      unsigned int stamp = (unsigned)(ph + 1);
      unsigned int* dst = h2b + (ph & 3) * 4096;
#pragma unroll
      for (int q = 0; q < 4; ++q) {
        float iv = acc[0][q], fv = acc[1][q], gg = acc[2][q], ov = acc[3][q];
        float cn = sigm(fv) * cst[q] + sigm(iv) * tanhf(gg);
        float hn = sigm(ov) * tanhf(cn);
        cst[q] = cn;
        st_hw(dst + (row + q) * 256 + j0 + lo4, ((unsigned)f2bf(hn) << 16) | stamp);
        oacc[q] += hn;
      }
      if (ph + 1 < T_SEQ) {  // shadow: consume h1[ph+1] (L1 is ahead), W2-part for ph+1
        poll_frag(h1b + ((ph + 1) & 3) * 4096 + fbase, (unsigned)(ph + 2), av);
        if (lane == 0) st_hw(&ctag[pid], (unsigned)(ph + 2));
#pragma unroll
        for (int g = 0; g < 4; ++g) acc[g] = (f32x4){bias[g], bias[g], bias[g], bias[g]};
#pragma unroll
        for (int kk = 0; kk < 8; ++kk)
#pragma unroll
          for (int g = 0; g < 4; ++g)
            acc[g] = __builtin_amdgcn_mfma_f32_16x16x32_bf16(av[kk], wB[0][kk][g], acc[g], 0, 0, 0);
      }
    }
#pragma unroll
    for (int q = 0; q < 4; ++q)
      out[(size_t)(b0 + row + q) * HID + j0 + lo4] = oacc[q] * (1.0f / T_SEQ);
  }
}

// ---------------- host ----------------

extern "C" void kernel_launch(void* const* d_in, const int* in_sizes, int n_in,
                              void* d_out, int out_size, void* d_ws, size_t ws_size,
                              hipStream_t stream) {
  const float* imu = (const float*)d_in[0];
  const float* k1 = (const float*)d_in[1];
  const float* g1 = (const float*)d_in[2];
  const float* b1 = (const float*)d_in[3];
  const float* m1 = (const float*)d_in[4];
  const float* v1 = (const float*)d_in[5];
  const float* k2 = (const float*)d_in[6];
  const float* g2 = (const float*)d_in[7];
  const float* b2 = (const float*)d_in[8];
  const float* m2 = (const float*)d_in[9];
  const float* v2 = (const float*)d_in[10];
  const float* k3 = (const float*)d_in[11];
  const float* g3 = (const float*)d_in[12];
  const float* b3 = (const float*)d_in[13];
  const float* m3 = (const float*)d_in[14];
  const float* v3 = (const float*)d_in[15];
  const float* W1 = (const float*)d_in[16];
  const float* U1 = (const float*)d_in[17];
  const float* bl1 = (const float*)d_in[18];
  const float* W2 = (const float*)d_in[19];
  const float* U2 = (const float*)d_in[20];
  const float* bl2 = (const float*)d_in[21];

  char* ws = (char*)d_ws;
  // [0,64Mi) y2 fp32; [64Mi,96Mi) y1 fp32; [64Mi,128Mi) x bf16 (y1 dead after conv2);
  // [128Mi..) u32 h rings (1Mi) + consumed tags (1Ki).
  float* y2 = (float*)ws;
  float* y1 = (float*)(ws + (64u << 20));
  unsigned short* xq = (unsigned short*)(ws + (64u << 20));
  unsigned int* hrings = (unsigned int*)(ws + (128u << 20));
  unsigned int* tags = (unsigned int*)(ws + (128u << 20) + (1u << 20));

  hipMemsetAsync(ws + (128u << 20), 0, (1u << 20) + 1024, stream);

  conv1_kernel<<<32768, 256, 0, stream>>>(imu, k1, g1, b1, m1, v1, y1);
  conv2_kernel<<<8192, 128, 0, stream>>>(y1, k2, g2, b2, m2, v2, y2);
  conv3_kernel<<<8192, 128, 0, stream>>>(y2, k3, g3, b3, m3, v3, xq);
  lstm_kernel<<<256, 64, 0, stream>>>(xq, W1, U1, bl1, W2, U2, bl2, hrings, tags,
                                      (float*)d_out);
}